// Round 1
// baseline (15424.477 us; speedup 1.0000x reference)
//
#include <hip/hip_runtime.h>

#define DEV __device__ __forceinline__

DEV float sigmoidf_(float x) { return 1.0f / (1.0f + __expf(-x)); }
DEV float tanhf2_(float x)   { return 1.0f - 2.0f / (__expf(2.0f * x) + 1.0f); }

// ---------------------------------------------------------------------------
// Weight prep: reorder LSTM weights so gates are interleaved per hidden unit:
// row (u*4+g) of dst = row (g*256+u) of src.  bias = b_ih + b_hh, interleaved.
// ---------------------------------------------------------------------------
__global__ void interleave_w_kernel(const float* __restrict__ src,
                                    float* __restrict__ dst, int K) {
    int idx = blockIdx.x * 256 + threadIdx.x;
    if (idx >= 1024 * K) return;
    int r = idx / K, k = idx - r * K;
    int u = r >> 2, g = r & 3;
    dst[idx] = src[(g * 256 + u) * K + k];
}

__global__ void interleave_b_kernel(const float* __restrict__ bi,
                                    const float* __restrict__ bh,
                                    float* __restrict__ dst) {
    int r = blockIdx.x * 256 + threadIdx.x;
    if (r >= 1024) return;
    int u = r >> 2, g = r & 3;
    dst[r] = bi[g * 256 + u] + bh[g * 256 + u];
}

// ---------------------------------------------------------------------------
// Fused LSTM step: gates = xin @ wih^T + h_prev @ whh^T + bias (interleaved),
// then cell update.  Tile 128 nodes x 128 gate-cols, 8x8 micro-tile.
// ---------------------------------------------------------------------------
__global__ __launch_bounds__(256) void lstm_step_kernel(
    const float* __restrict__ xin, int xstride, int xoff, int Kin,
    const float* __restrict__ wih,   // [1024, Kin] interleaved rows
    const float* __restrict__ whh,   // [1024, 256] interleaved rows
    const float* __restrict__ bias,  // [1024] interleaved
    const float* __restrict__ h_prev,
    float* __restrict__ c_state,     // in-place
    float* __restrict__ h_out, int M)
{
    __shared__ float sA[16][136];
    __shared__ float sB[16][136];
    const int tid = threadIdx.x;
    const int m0 = blockIdx.x * 128, n0 = blockIdx.y * 128;
    const int tx = tid & 15, ty = tid >> 4;
    const int lam = tid >> 1, lak = (tid & 1) * 8;

    float acc[8][8];
#pragma unroll
    for (int i = 0; i < 8; ++i)
#pragma unroll
        for (int j = 0; j < 8; ++j) acc[i][j] = 0.f;

#pragma unroll 1
    for (int ph = 0; ph < 2; ++ph) {
        const float* Ap = ph ? h_prev : xin;
        const int As = ph ? 256 : xstride;
        const int Ao = ph ? 0 : xoff;
        const float* Wp = ph ? whh : wih;
        const int KK = ph ? 256 : Kin;
        for (int k0 = 0; k0 < KK; k0 += 16) {
            float4 a0 = {0.f, 0.f, 0.f, 0.f}, a1 = {0.f, 0.f, 0.f, 0.f};
            int am = m0 + lam;
            if (am < M) {
                const float* ap = Ap + (size_t)am * As + Ao + k0 + lak;
                a0 = *(const float4*)ap;
                a1 = *(const float4*)(ap + 4);
            }
            const float* wp = Wp + (size_t)(n0 + lam) * KK + k0 + lak;
            float4 b0 = *(const float4*)wp;
            float4 b1 = *(const float4*)(wp + 4);
            __syncthreads();
            sA[lak + 0][lam] = a0.x; sA[lak + 1][lam] = a0.y;
            sA[lak + 2][lam] = a0.z; sA[lak + 3][lam] = a0.w;
            sA[lak + 4][lam] = a1.x; sA[lak + 5][lam] = a1.y;
            sA[lak + 6][lam] = a1.z; sA[lak + 7][lam] = a1.w;
            sB[lak + 0][lam] = b0.x; sB[lak + 1][lam] = b0.y;
            sB[lak + 2][lam] = b0.z; sB[lak + 3][lam] = b0.w;
            sB[lak + 4][lam] = b1.x; sB[lak + 5][lam] = b1.y;
            sB[lak + 6][lam] = b1.z; sB[lak + 7][lam] = b1.w;
            __syncthreads();
#pragma unroll
            for (int k = 0; k < 16; ++k) {
                float4 A0 = *(const float4*)&sA[k][ty * 4];
                float4 A1 = *(const float4*)&sA[k][64 + ty * 4];
                float4 B0 = *(const float4*)&sB[k][tx * 4];
                float4 B1 = *(const float4*)&sB[k][64 + tx * 4];
                float av[8] = {A0.x, A0.y, A0.z, A0.w, A1.x, A1.y, A1.z, A1.w};
                float bv[8] = {B0.x, B0.y, B0.z, B0.w, B1.x, B1.y, B1.z, B1.w};
#pragma unroll
                for (int i = 0; i < 8; ++i)
#pragma unroll
                    for (int j = 0; j < 8; ++j)
                        acc[i][j] = fmaf(av[i], bv[j], acc[i][j]);
            }
        }
    }

    // epilogue: gates -> cell update.  col quad (4 gates) = one hidden unit.
#pragma unroll
    for (int i = 0; i < 8; ++i) {
        int m = m0 + ((i < 4) ? (ty * 4 + i) : (60 + ty * 4 + i));
        if (m < M) {
#pragma unroll
            for (int ci = 0; ci < 2; ++ci) {
                int colbase = n0 + ci * 64 + tx * 4;
                int U = colbase >> 2;
                float gi = sigmoidf_(acc[i][ci * 4 + 0] + bias[colbase + 0]);
                float gf = sigmoidf_(acc[i][ci * 4 + 1] + bias[colbase + 1]);
                float gg = tanhf2_(acc[i][ci * 4 + 2] + bias[colbase + 2]);
                float go = sigmoidf_(acc[i][ci * 4 + 3] + bias[colbase + 3]);
                float cold = c_state[(size_t)m * 256 + U];
                float cn = gf * cold + gi * gg;
                c_state[(size_t)m * 256 + U] = cn;
                h_out[(size_t)m * 256 + U] = go * tanhf2_(cn);
            }
        }
    }
}

// ---------------------------------------------------------------------------
// Generic fp32 GEMM: C = act(A[MxK] @ B[KxN] + bias), row-major, N%128==0, K%16==0
// ---------------------------------------------------------------------------
__global__ __launch_bounds__(256) void gemm_kernel(
    const float* __restrict__ A, const float* __restrict__ B,
    const float* __restrict__ bias, float* __restrict__ C,
    int M, int N, int K, int relu)
{
    __shared__ float sA[16][136];
    __shared__ float sB[16][136];
    const int tid = threadIdx.x;
    const int m0 = blockIdx.x * 128, n0 = blockIdx.y * 128;
    const int tx = tid & 15, ty = tid >> 4;
    const int lam = tid >> 1, lak = (tid & 1) * 8;
    const int lbk = tid >> 4, lbn = (tid & 15) * 8;

    float acc[8][8];
#pragma unroll
    for (int i = 0; i < 8; ++i)
#pragma unroll
        for (int j = 0; j < 8; ++j) acc[i][j] = 0.f;

    for (int k0 = 0; k0 < K; k0 += 16) {
        float4 a0 = {0.f, 0.f, 0.f, 0.f}, a1 = {0.f, 0.f, 0.f, 0.f};
        int am = m0 + lam;
        if (am < M) {
            const float* ap = A + (size_t)am * K + k0 + lak;
            a0 = *(const float4*)ap;
            a1 = *(const float4*)(ap + 4);
        }
        const float* bp = B + (size_t)(k0 + lbk) * N + n0 + lbn;
        float4 b0 = *(const float4*)bp;
        float4 b1 = *(const float4*)(bp + 4);
        __syncthreads();
        sA[lak + 0][lam] = a0.x; sA[lak + 1][lam] = a0.y;
        sA[lak + 2][lam] = a0.z; sA[lak + 3][lam] = a0.w;
        sA[lak + 4][lam] = a1.x; sA[lak + 5][lam] = a1.y;
        sA[lak + 6][lam] = a1.z; sA[lak + 7][lam] = a1.w;
        *(float4*)&sB[lbk][lbn] = b0;
        *(float4*)&sB[lbk][lbn + 4] = b1;
        __syncthreads();
#pragma unroll
        for (int k = 0; k < 16; ++k) {
            float4 A0 = *(const float4*)&sA[k][ty * 4];
            float4 A1 = *(const float4*)&sA[k][64 + ty * 4];
            float4 B0 = *(const float4*)&sB[k][tx * 4];
            float4 B1 = *(const float4*)&sB[k][64 + tx * 4];
            float av[8] = {A0.x, A0.y, A0.z, A0.w, A1.x, A1.y, A1.z, A1.w};
            float bv[8] = {B0.x, B0.y, B0.z, B0.w, B1.x, B1.y, B1.z, B1.w};
#pragma unroll
            for (int i = 0; i < 8; ++i)
#pragma unroll
                for (int j = 0; j < 8; ++j)
                    acc[i][j] = fmaf(av[i], bv[j], acc[i][j]);
        }
    }

#pragma unroll
    for (int i = 0; i < 8; ++i) {
        int m = m0 + ((i < 4) ? (ty * 4 + i) : (60 + ty * 4 + i));
        if (m >= M) continue;
#pragma unroll
        for (int j = 0; j < 8; ++j) {
            int n = n0 + ((j < 4) ? (tx * 4 + j) : (60 + tx * 4 + j));
            float v = acc[i][j] + bias[n];
            if (relu) v = fmaxf(v, 0.f);
            C[(size_t)m * N + n] = v;
        }
    }
}

// ---------------------------------------------------------------------------
// Edge preprocessing: mean of edge_attr, CSR by dst (hist / scan / scatter)
// ---------------------------------------------------------------------------
__global__ void mean_kernel(const float* __restrict__ a, int n, float* __restrict__ out) {
    __shared__ float s[256];
    float loc = 0.f;
    for (int i = threadIdx.x; i < n; i += 256) loc += a[i];
    s[threadIdx.x] = loc;
    __syncthreads();
    for (int off = 128; off; off >>= 1) {
        if (threadIdx.x < off) s[threadIdx.x] += s[threadIdx.x + off];
        __syncthreads();
    }
    if (threadIdx.x == 0) out[0] = s[0] / (float)n;
}

__global__ void hist_kernel(const int* __restrict__ ei, int Ne, int Nn,
                            int* __restrict__ counts) {
    int e = blockIdx.x * 256 + threadIdx.x;
    if (e >= Ne + Nn) return;
    int d = (e < Ne) ? ei[Ne + e] : (e - Ne);
    atomicAdd(&counts[d], 1);
}

__global__ void scan_kernel(const int* __restrict__ counts, int* __restrict__ offsets, int n) {
    __shared__ int s[256];
    int tid = threadIdx.x;
    int chunk = (n + 255) / 256;
    int b = tid * chunk;
    int loc = 0;
    for (int j = 0; j < chunk; ++j) { int i = b + j; if (i < n) loc += counts[i]; }
    s[tid] = loc;
    __syncthreads();
    for (int off = 1; off < 256; off <<= 1) {
        int v = (tid >= off) ? s[tid - off] : 0;
        __syncthreads();
        s[tid] += v;
        __syncthreads();
    }
    int run = (tid == 0) ? 0 : s[tid - 1];
    for (int j = 0; j < chunk; ++j) {
        int i = b + j;
        if (i < n) { offsets[i] = run; run += counts[i]; }
    }
    if (tid == 255) offsets[n] = run;
}

__global__ void scatter_kernel(const int* __restrict__ ei, const float* __restrict__ ea,
                               const float* __restrict__ meanp, int Ne, int Nn,
                               int* __restrict__ cursor, int* __restrict__ src_sorted,
                               float* __restrict__ ea_sorted) {
    int e = blockIdx.x * 256 + threadIdx.x;
    if (e >= Ne + Nn) return;
    int s, d; float a;
    if (e < Ne) { s = ei[e]; d = ei[Ne + e]; a = ea[e]; }
    else        { s = e - Ne; d = s; a = meanp[0]; }
    int pos = atomicAdd(&cursor[d], 1);
    src_sorted[pos] = s;
    ea_sorted[pos] = a;
}

// ---------------------------------------------------------------------------
// GATv2 attention + aggregation, one block per dst node (gather over CSR).
// out[i,:] = elu( sum_e alpha[e,h] * xl[src_e,:] + bias )
// ---------------------------------------------------------------------------
__global__ __launch_bounds__(256) void gat_aggregate_kernel(
    const float* __restrict__ xl, const float* __restrict__ xr,
    const float* __restrict__ we, const float* __restrict__ att,
    const float* __restrict__ bias,
    const int* __restrict__ offsets, const int* __restrict__ src_sorted,
    const float* __restrict__ ea_sorted,
    float* __restrict__ logit_buf, float* __restrict__ out, int N)
{
    __shared__ float s_xr[512], s_we[512], s_att[512];
    __shared__ float s_wmax[32], s_mx[8], s_den[8], s_rden[8];
    __shared__ float s_alpha[256];
    __shared__ int s_src[32];
    const int i = blockIdx.x;
    const int tid = threadIdx.x;
    s_xr[tid] = xr[(size_t)i * 512 + tid];
    s_xr[tid + 256] = xr[(size_t)i * 512 + tid + 256];
    s_we[tid] = we[tid]; s_we[tid + 256] = we[tid + 256];
    s_att[tid] = att[tid]; s_att[tid + 256] = att[tid + 256];
    if (tid < 8) s_den[tid] = 0.f;
    __syncthreads();

    const int beg = offsets[i], end = offsets[i + 1];
    const int w = tid >> 6, lane = tid & 63;

    // pass A: logits + per-wave running max
    float wmax[8];
#pragma unroll
    for (int h = 0; h < 8; ++h) wmax[h] = -1e30f;
    for (int e = beg + w; e < end; e += 4) {
        int s = src_sorted[e];
        float a = ea_sorted[e];
        float lg[8];
#pragma unroll
        for (int h = 0; h < 8; ++h) {
            int c = h * 64 + lane;
            float v = xl[(size_t)s * 512 + c] + s_xr[c] + a * s_we[c];
            v = (v > 0.f) ? v : 0.2f * v;
            lg[h] = v * s_att[c];
        }
#pragma unroll
        for (int off = 32; off; off >>= 1)
#pragma unroll
            for (int h = 0; h < 8; ++h) lg[h] += __shfl_xor(lg[h], off, 64);
#pragma unroll
        for (int h = 0; h < 8; ++h) {
            wmax[h] = fmaxf(wmax[h], lg[h]);
            if (lane == h) logit_buf[(size_t)e * 8 + h] = lg[h];
        }
    }
    if (lane == 0) {
#pragma unroll
        for (int h = 0; h < 8; ++h) s_wmax[w * 8 + h] = wmax[h];
    }
    __syncthreads();
    if (tid < 8) {
        float m = fmaxf(fmaxf(s_wmax[tid], s_wmax[8 + tid]),
                        fmaxf(s_wmax[16 + tid], s_wmax[24 + tid]));
        s_mx[tid] = m;
    }
    __syncthreads();

    // pass B: exp + denominator
    for (int e = beg + tid; e < end; e += 256) {
#pragma unroll
        for (int h = 0; h < 8; ++h) {
            float ex = __expf(logit_buf[(size_t)e * 8 + h] - s_mx[h]);
            logit_buf[(size_t)e * 8 + h] = ex;
            atomicAdd(&s_den[h], ex);
        }
    }
    __syncthreads();
    if (tid < 8) s_rden[tid] = 1.f / s_den[tid];
    __syncthreads();

    // pass C: weighted aggregation (chunked alpha staging)
    float acc0 = 0.f, acc1 = 0.f;
    const int h0 = tid >> 6, h1 = (tid + 256) >> 6;
    for (int chunk = beg; chunk < end; chunk += 32) {
        int cnt = min(32, end - chunk);
        if (tid < cnt) s_src[tid] = src_sorted[chunk + tid];
        int eo = tid >> 3, hh = tid & 7;
        if (eo < cnt) s_alpha[tid] = logit_buf[(size_t)(chunk + eo) * 8 + hh] * s_rden[hh];
        __syncthreads();
        for (int j = 0; j < cnt; ++j) {
            int s = s_src[j];
            acc0 += s_alpha[j * 8 + h0] * xl[(size_t)s * 512 + tid];
            acc1 += s_alpha[j * 8 + h1] * xl[(size_t)s * 512 + tid + 256];
        }
        __syncthreads();
    }
    float v0 = acc0 + bias[tid];
    float v1 = acc1 + bias[tid + 256];
    v0 = (v0 > 0.f) ? v0 : __expf(v0) - 1.f;
    v1 = (v1 > 0.f) ? v1 : __expf(v1) - 1.f;
    out[(size_t)i * 512 + tid] = v0;
    out[(size_t)i * 512 + tid + 256] = v1;
}

// ---------------------------------------------------------------------------
// concat [node | g] -> fused [N,768]
// ---------------------------------------------------------------------------
__global__ void concat_kernel(const float* __restrict__ node, const float* __restrict__ g,
                              float* __restrict__ fused, int N) {
    int idx = blockIdx.x * 256 + threadIdx.x;
    if (idx >= N * 768) return;
    int n = idx / 768, c = idx - n * 768;
    fused[idx] = (c < 256) ? node[(size_t)n * 256 + c] : g[(size_t)n * 512 + c - 256];
}

// ---------------------------------------------------------------------------
// fc2: out[n] = H[n,:512] . w + b   (one wave per node)
// ---------------------------------------------------------------------------
__global__ void fc2_kernel(const float* __restrict__ H, const float* __restrict__ w,
                           const float* __restrict__ b, float* __restrict__ out, int N) {
    int wv = threadIdx.x >> 6, lane = threadIdx.x & 63;
    int node = blockIdx.x * 4 + wv;
    if (node >= N) return;
    float s = 0.f;
#pragma unroll
    for (int j = 0; j < 8; ++j)
        s += H[(size_t)node * 512 + j * 64 + lane] * w[j * 64 + lane];
#pragma unroll
    for (int off = 32; off; off >>= 1) s += __shfl_xor(s, off, 64);
    if (lane == 0) out[node] = s + b[0];
}

// ---------------------------------------------------------------------------
extern "C" void kernel_launch(void* const* d_in, const int* in_sizes, int n_in,
                              void* d_out, int out_size, void* d_ws, size_t ws_size,
                              hipStream_t stream) {
    const float* x_seq     = (const float*)d_in[0];
    const int*   edge_index= (const int*)d_in[1];
    const float* edge_attr = (const float*)d_in[2];
    const float* w_ih0 = (const float*)d_in[3];
    const float* w_hh0 = (const float*)d_in[4];
    const float* b_ih0 = (const float*)d_in[5];
    const float* b_hh0 = (const float*)d_in[6];
    const float* w_ih1 = (const float*)d_in[7];
    const float* w_hh1 = (const float*)d_in[8];
    const float* b_ih1 = (const float*)d_in[9];
    const float* b_hh1 = (const float*)d_in[10];
    const float* g0_wl = (const float*)d_in[11];
    const float* g0_bl = (const float*)d_in[12];
    const float* g0_wr = (const float*)d_in[13];
    const float* g0_br = (const float*)d_in[14];
    const float* g0_we = (const float*)d_in[15];
    const float* g0_att= (const float*)d_in[16];
    const float* g0_bias=(const float*)d_in[17];
    const float* g1_wl = (const float*)d_in[18];
    const float* g1_bl = (const float*)d_in[19];
    const float* g1_wr = (const float*)d_in[20];
    const float* g1_br = (const float*)d_in[21];
    const float* g1_we = (const float*)d_in[22];
    const float* g1_att= (const float*)d_in[23];
    const float* g1_bias=(const float*)d_in[24];
    const float* fc1_w = (const float*)d_in[25];
    const float* fc1_b = (const float*)d_in[26];
    const float* fc2_w = (const float*)d_in[27];
    const float* fc2_b = (const float*)d_in[28];
    float* out = (float*)d_out;

    const int Nn = in_sizes[0] / (60 * 16);  // 10000
    const int Ne = in_sizes[1] / 2;          // 320000
    const int Etot = Ne + Nn;
    const int NS = Nn * 256;
    const int MT = (Nn + 127) / 128;

    // ---- workspace layout (bytes, 256-aligned bumps) ----
    size_t off = 0;
    auto alloc = [&](size_t bytes) -> void* {
        void* r = (char*)d_ws + off;
        off += (bytes + 255) & ~(size_t)255;
        return r;
    };
    float* wih0i = (float*)alloc((size_t)1024 * 16 * 4);
    float* whh0i = (float*)alloc((size_t)1024 * 256 * 4);
    float* wih1i = (float*)alloc((size_t)1024 * 256 * 4);
    float* whh1i = (float*)alloc((size_t)1024 * 256 * 4);
    float* b0i   = (float*)alloc(1024 * 4);
    float* b1i   = (float*)alloc(1024 * 4);
    float* lstm_state = (float*)alloc((size_t)6 * NS * 4);
    float* h0_0 = lstm_state;
    float* h0_1 = lstm_state + (size_t)NS;
    float* c0   = lstm_state + (size_t)2 * NS;
    float* h1_1 = lstm_state + (size_t)3 * NS;
    float* c1   = lstm_state + (size_t)4 * NS;
    float* h1_0 = lstm_state + (size_t)5 * NS;
    int* counts  = (int*)alloc((size_t)Nn * 4);
    int* offsets = (int*)alloc((size_t)(Nn + 1) * 4);
    int* cursor  = (int*)alloc((size_t)Nn * 4);
    int* src_sorted = (int*)alloc((size_t)Etot * 4);
    float* ea_sorted = (float*)alloc((size_t)Etot * 4);
    float* meanp = (float*)alloc(256);
    float* xl = (float*)alloc((size_t)Nn * 512 * 4);
    float* xr = (float*)alloc((size_t)Nn * 512 * 4);
    float* gbuf = (float*)alloc((size_t)Nn * 512 * 4);
    float* logit_buf = (float*)alloc((size_t)Etot * 8 * 4);
    // aliases into dead LSTM state (safe: used only after LSTM finishes)
    float* fused = h0_0;   // Nn*768 == 3*NS
    float* hfc1  = h1_1;   // Nn*512 == 2*NS (h1_1 + c1), h1_0 (node) untouched

    // ---- weight prep ----
    interleave_w_kernel<<<dim3((1024 * 16 + 255) / 256), 256, 0, stream>>>(w_ih0, wih0i, 16);
    interleave_w_kernel<<<dim3((1024 * 256 + 255) / 256), 256, 0, stream>>>(w_hh0, whh0i, 256);
    interleave_w_kernel<<<dim3((1024 * 256 + 255) / 256), 256, 0, stream>>>(w_ih1, wih1i, 256);
    interleave_w_kernel<<<dim3((1024 * 256 + 255) / 256), 256, 0, stream>>>(w_hh1, whh1i, 256);
    interleave_b_kernel<<<dim3(4), 256, 0, stream>>>(b_ih0, b_hh0, b0i);
    interleave_b_kernel<<<dim3(4), 256, 0, stream>>>(b_ih1, b_hh1, b1i);
    hipMemsetAsync(lstm_state, 0, (size_t)6 * NS * 4, stream);

    // ---- edge prep (CSR by dst) ----
    mean_kernel<<<dim3(1), 256, 0, stream>>>(edge_attr, Ne, meanp);
    hipMemsetAsync(counts, 0, (size_t)Nn * 4, stream);
    hist_kernel<<<dim3((Etot + 255) / 256), 256, 0, stream>>>(edge_index, Ne, Nn, counts);
    scan_kernel<<<dim3(1), 256, 0, stream>>>(counts, offsets, Nn);
    hipMemcpyAsync(cursor, offsets, (size_t)Nn * 4, hipMemcpyDeviceToDevice, stream);
    scatter_kernel<<<dim3((Etot + 255) / 256), 256, 0, stream>>>(
        edge_index, edge_attr, meanp, Ne, Nn, cursor, src_sorted, ea_sorted);

    // ---- 2-layer LSTM, 60 steps ----
    dim3 lgrid(MT, 8);
    for (int t = 0; t < 60; ++t) {
        const float* hin0 = (t & 1) ? h0_1 : h0_0;
        float* hout0      = (t & 1) ? h0_0 : h0_1;
        lstm_step_kernel<<<lgrid, 256, 0, stream>>>(
            x_seq, 960, t * 16, 16, wih0i, whh0i, b0i, hin0, c0, hout0, Nn);
        const float* hin1 = (t & 1) ? h1_1 : h1_0;
        float* hout1      = (t & 1) ? h1_0 : h1_1;
        lstm_step_kernel<<<lgrid, 256, 0, stream>>>(
            hout0, 256, 0, 256, wih1i, whh1i, b1i, hin1, c1, hout1, Nn);
    }
    const float* node = h1_0;  // h2[-1]

    // ---- GAT layer 1 ----
    dim3 ggrid(MT, 4);
    gemm_kernel<<<ggrid, 256, 0, stream>>>(node, g0_wl, g0_bl, xl, Nn, 512, 256, 0);
    gemm_kernel<<<ggrid, 256, 0, stream>>>(node, g0_wr, g0_br, xr, Nn, 512, 256, 0);
    gat_aggregate_kernel<<<dim3(Nn), 256, 0, stream>>>(
        xl, xr, g0_we, g0_att, g0_bias, offsets, src_sorted, ea_sorted, logit_buf, gbuf, Nn);

    // ---- GAT layer 2 ----
    gemm_kernel<<<ggrid, 256, 0, stream>>>(gbuf, g1_wl, g1_bl, xl, Nn, 512, 512, 0);
    gemm_kernel<<<ggrid, 256, 0, stream>>>(gbuf, g1_wr, g1_br, xr, Nn, 512, 512, 0);
    gat_aggregate_kernel<<<dim3(Nn), 256, 0, stream>>>(
        xl, xr, g1_we, g1_att, g1_bias, offsets, src_sorted, ea_sorted, logit_buf, gbuf, Nn);

    // ---- fusion MLP ----
    concat_kernel<<<dim3((Nn * 768 + 255) / 256), 256, 0, stream>>>(node, gbuf, fused, Nn);
    gemm_kernel<<<ggrid, 256, 0, stream>>>(fused, fc1_w, fc1_b, hfc1, Nn, 512, 768, 1);
    fc2_kernel<<<dim3((Nn + 3) / 4), 256, 0, stream>>>(hfc1, fc2_w, fc2_b, out, Nn);
}

// Round 2
// 3941.289 us; speedup vs baseline: 3.9136x; 3.9136x over previous
//
#include <hip/hip_runtime.h>

#define DEV __device__ __forceinline__

typedef _Float16 f16;
typedef _Float16 f16x8 __attribute__((ext_vector_type(8)));
typedef _Float16 f16x2 __attribute__((ext_vector_type(2)));
typedef float f32x4 __attribute__((ext_vector_type(4)));

DEV float sigmoidf_(float x) { return 1.0f / (1.0f + __expf(-x)); }
DEV float tanhf2_(float x)   { return 1.0f - 2.0f / (__expf(2.0f * x) + 1.0f); }

// async global->LDS, 16B per lane. LDS dest = wave-uniform base + lane*16.
DEV void load_lds16(const void* g, void* l) {
    __builtin_amdgcn_global_load_lds(
        (const __attribute__((address_space(1))) char*)(const char*)g,
        (__attribute__((address_space(3))) char*)(unsigned int)(unsigned long long)(char*)l,
        16, 0, 0);
}

// ---------------------------------------------------------------------------
// LSTM weight prep: Wt[1024][K] fp16, column-order chosen so that in the MFMA
// C-layout the 4 gates of a unit land in one lane's 4 j-fragments.
// dst row rd: T=rd>>7, p=rd&127, wh=(p>>6)&1, j=(p>>4)&3, c=p&15
//   unit u = T*32 + wh*16 + c ; gate g = j ; src row = g*256+u
// ---------------------------------------------------------------------------
__global__ void prep_w0_kernel(const float* __restrict__ wih,
                               const float* __restrict__ whh,
                               f16* __restrict__ dst) {   // [1024,288]
    int idx = blockIdx.x * 256 + threadIdx.x;
    if (idx >= 1024 * 288) return;
    int rd = idx / 288, k = idx - rd * 288;
    int T = rd >> 7, p = rd & 127;
    int u = T * 32 + ((p >> 6) & 1) * 16 + (p & 15);
    int g = (p >> 4) & 3;
    int src = g * 256 + u;
    float v;
    if (k < 16)        v = wih[src * 16 + k];
    else if (k < 272)  v = whh[src * 256 + (k - 16)];
    else               v = 0.f;
    dst[idx] = (f16)v;
}

__global__ void prep_w1_kernel(const float* __restrict__ wih,
                               const float* __restrict__ whh,
                               f16* __restrict__ dst) {   // [1024,512]
    int idx = blockIdx.x * 256 + threadIdx.x;
    if (idx >= 1024 * 512) return;
    int rd = idx >> 9, k = idx & 511;
    int T = rd >> 7, p = rd & 127;
    int u = T * 32 + ((p >> 6) & 1) * 16 + (p & 15);
    int g = (p >> 4) & 3;
    int src = g * 256 + u;
    float v = (k < 256) ? wih[src * 256 + k] : whh[src * 256 + (k - 256)];
    dst[idx] = (f16)v;
}

__global__ void prep_bias4_kernel(const float* __restrict__ bi,
                                  const float* __restrict__ bh,
                                  float* __restrict__ dst) {  // [1024] = [u*4+g]
    int idx = blockIdx.x * 256 + threadIdx.x;
    if (idx >= 1024) return;
    int u = idx >> 2, g = idx & 3;
    dst[idx] = bi[g * 256 + u] + bh[g * 256 + u];
}

// generic [K,N] fp32 -> [N,K] fp16 transpose
__global__ void prep_wt_kernel(const float* __restrict__ src, f16* __restrict__ dst,
                               int K, int N) {
    int idx = blockIdx.x * 256 + threadIdx.x;
    if (idx >= K * N) return;
    int n = idx / K, k = idx - n * K;
    dst[idx] = (f16)src[(size_t)k * N + n];
}

// x_seq[:,0,:16] -> A0buf0 cols 0..15
__global__ void prep_x0_kernel(const float* __restrict__ x_seq, f16* __restrict__ A0,
                               int Nn) {
    int idx = blockIdx.x * 256 + threadIdx.x;
    if (idx >= Nn * 16) return;
    int m = idx >> 4, f = idx & 15;
    A0[(size_t)m * 288 + f] = (f16)x_seq[(size_t)m * 960 + f];
}

// ---------------------------------------------------------------------------
// Fused LSTM step (f16 MFMA): gates = A @ Wt^T (+bias), cell update.
// A [Mpad,lda] fp16, Wt [1024,K] fp16, K%32==0. Tile 128x128, 4 waves 2x2.
// ---------------------------------------------------------------------------
__global__ __launch_bounds__(256) void lstm_mfma_kernel(
    const f16* __restrict__ A, int lda, int K,
    const f16* __restrict__ Wt,
    const float* __restrict__ bias4,
    float* __restrict__ c_state,
    f16* __restrict__ hA, int ldhA, int offhA,
    f16* __restrict__ hB, int ldhB, int offhB,
    const float* __restrict__ xsrc, int tnext,
    int M)
{
    __shared__ __align__(16) f16 sA[128 * 32];
    __shared__ __align__(16) f16 sB[128 * 32];
    const int tid = threadIdx.x;
    const int w = tid >> 6, lane = tid & 63;
    const int m0 = blockIdx.x * 128, n0 = blockIdx.y * 128;
    const int arow = lane >> 2, achk = (lane & 3) * 8;
    const int frow = lane & 15, fchk = (lane >> 4) * 8;
    const int wr = (w >> 1) * 64, wc = (w & 1) * 64;

    f32x4 acc[4][4] = {};

    for (int k0 = 0; k0 < K; k0 += 32) {
        __syncthreads();
#pragma unroll
        for (int c = 0; c < 2; ++c) {
            int R = c * 64 + w * 16;
            load_lds16(A + (size_t)(m0 + R + arow) * lda + k0 + achk, sA + R * 32);
            load_lds16(Wt + (size_t)(n0 + R + arow) * K + k0 + achk, sB + R * 32);
        }
        __syncthreads();
        f16x8 af[4], bf[4];
#pragma unroll
        for (int i = 0; i < 4; ++i)
            af[i] = *(const f16x8*)&sA[(wr + i * 16 + frow) * 32 + fchk];
#pragma unroll
        for (int j = 0; j < 4; ++j)
            bf[j] = *(const f16x8*)&sB[(wc + j * 16 + frow) * 32 + fchk];
#pragma unroll
        for (int i = 0; i < 4; ++i)
#pragma unroll
            for (int j = 0; j < 4; ++j)
                acc[i][j] = __builtin_amdgcn_mfma_f32_16x16x32_f16(af[i], bf[j], acc[i][j], 0, 0, 0);
    }

    // epilogue: lane owns unit u, acc[i][j][r] = gate j of row m
    const int u = blockIdx.y * 32 + (w & 1) * 16 + (lane & 15);
    const float4 bb = *(const float4*)&bias4[u * 4];
    const int rbase = m0 + wr + (lane >> 4) * 4;
#pragma unroll
    for (int i = 0; i < 4; ++i) {
#pragma unroll
        for (int r = 0; r < 4; ++r) {
            int m = rbase + i * 16 + r;
            if (m < M) {
                float gi = sigmoidf_(acc[i][0][r] + bb.x);
                float gf = sigmoidf_(acc[i][1][r] + bb.y);
                float gg = tanhf2_(acc[i][2][r] + bb.z);
                float go = sigmoidf_(acc[i][3][r] + bb.w);
                float cold = c_state[(size_t)m * 256 + u];
                float cn = gf * cold + gi * gg;
                c_state[(size_t)m * 256 + u] = cn;
                f16 h = (f16)(go * tanhf2_(cn));
                hA[(size_t)m * ldhA + offhA + u] = h;
                if (hB) hB[(size_t)m * ldhB + offhB + u] = h;
            }
        }
    }
    // layer0 blocks (y==0) stage x_{t+1} into A0next cols 0..15
    if (xsrc && blockIdx.y == 0) {
        int row = tid >> 1, fb = (tid & 1) * 8;
        int m = m0 + row;
        if (m < M) {
            const float* xp = xsrc + (size_t)m * 960 + tnext * 16 + fb;
            f16* dp = hB + (size_t)m * ldhB + fb;
#pragma unroll
            for (int q = 0; q < 8; ++q) dp[q] = (f16)xp[q];
        }
    }
}

// ---------------------------------------------------------------------------
// Generic f16 MFMA GEMM: C = act(A[M,lda(K cols)] @ Bt[N,K]^T + bias)
// out either fp16 (C16) or fp32 (C32). act: 0 none, 1 relu.
// ---------------------------------------------------------------------------
__global__ __launch_bounds__(256) void gemm16_kernel(
    const f16* __restrict__ A, int lda,
    const f16* __restrict__ Bt, int K,
    const float* __restrict__ bias,
    f16* __restrict__ C16, float* __restrict__ C32, int ldc,
    int act, int M)
{
    __shared__ __align__(16) f16 sA[128 * 32];
    __shared__ __align__(16) f16 sB[128 * 32];
    const int tid = threadIdx.x;
    const int w = tid >> 6, lane = tid & 63;
    const int m0 = blockIdx.x * 128, n0 = blockIdx.y * 128;
    const int arow = lane >> 2, achk = (lane & 3) * 8;
    const int frow = lane & 15, fchk = (lane >> 4) * 8;
    const int wr = (w >> 1) * 64, wc = (w & 1) * 64;

    f32x4 acc[4][4] = {};

    for (int k0 = 0; k0 < K; k0 += 32) {
        __syncthreads();
#pragma unroll
        for (int c = 0; c < 2; ++c) {
            int R = c * 64 + w * 16;
            load_lds16(A + (size_t)(m0 + R + arow) * lda + k0 + achk, sA + R * 32);
            load_lds16(Bt + (size_t)(n0 + R + arow) * K + k0 + achk, sB + R * 32);
        }
        __syncthreads();
        f16x8 af[4], bf[4];
#pragma unroll
        for (int i = 0; i < 4; ++i)
            af[i] = *(const f16x8*)&sA[(wr + i * 16 + frow) * 32 + fchk];
#pragma unroll
        for (int j = 0; j < 4; ++j)
            bf[j] = *(const f16x8*)&sB[(wc + j * 16 + frow) * 32 + fchk];
#pragma unroll
        for (int i = 0; i < 4; ++i)
#pragma unroll
            for (int j = 0; j < 4; ++j)
                acc[i][j] = __builtin_amdgcn_mfma_f32_16x16x32_f16(af[i], bf[j], acc[i][j], 0, 0, 0);
    }

    const int rbase = m0 + wr + (lane >> 4) * 4;
#pragma unroll
    for (int i = 0; i < 4; ++i) {
#pragma unroll
        for (int r = 0; r < 4; ++r) {
            int m = rbase + i * 16 + r;
            if (m >= M) continue;
#pragma unroll
            for (int j = 0; j < 4; ++j) {
                int n = n0 + wc + j * 16 + (lane & 15);
                float v = acc[i][j][r] + bias[n];
                if (act == 1) v = fmaxf(v, 0.f);
                if (C16) C16[(size_t)m * ldc + n] = (f16)v;
                else     C32[(size_t)m * ldc + n] = v;
            }
        }
    }
}

// ---------------------------------------------------------------------------
// Edge preprocessing
// ---------------------------------------------------------------------------
__global__ void mean_sum_kernel(const float* __restrict__ a, int n, float* __restrict__ out) {
    __shared__ float s[256];
    float loc = 0.f;
    for (int i = blockIdx.x * 256 + threadIdx.x; i < n; i += gridDim.x * 256) loc += a[i];
    s[threadIdx.x] = loc;
    __syncthreads();
    for (int off = 128; off; off >>= 1) {
        if (threadIdx.x < off) s[threadIdx.x] += s[threadIdx.x + off];
        __syncthreads();
    }
    if (threadIdx.x == 0) atomicAdd(out, s[0]);
}

__global__ void hist_kernel(const int* __restrict__ ei, int Ne, int Nn,
                            int* __restrict__ counts) {
    int e = blockIdx.x * 256 + threadIdx.x;
    if (e >= Ne + Nn) return;
    int d = (e < Ne) ? ei[Ne + e] : (e - Ne);
    atomicAdd(&counts[d], 1);
}

__global__ void scan_kernel(const int* __restrict__ counts, int* __restrict__ offsets, int n) {
    __shared__ int s[256];
    int tid = threadIdx.x;
    int chunk = (n + 255) / 256;
    int b = tid * chunk;
    int loc = 0;
    for (int j = 0; j < chunk; ++j) { int i = b + j; if (i < n) loc += counts[i]; }
    s[tid] = loc;
    __syncthreads();
    for (int off = 1; off < 256; off <<= 1) {
        int v = (tid >= off) ? s[tid - off] : 0;
        __syncthreads();
        s[tid] += v;
        __syncthreads();
    }
    int run = (tid == 0) ? 0 : s[tid - 1];
    for (int j = 0; j < chunk; ++j) {
        int i = b + j;
        if (i < n) { offsets[i] = run; run += counts[i]; }
    }
    if (tid == 255) offsets[n] = run;
}

__global__ void scatter_kernel(const int* __restrict__ ei, const float* __restrict__ ea,
                               const float* __restrict__ sump, float inv_ne, int Ne, int Nn,
                               int* __restrict__ cursor, int* __restrict__ src_sorted,
                               float* __restrict__ ea_sorted) {
    int e = blockIdx.x * 256 + threadIdx.x;
    if (e >= Ne + Nn) return;
    int s, d; float a;
    if (e < Ne) { s = ei[e]; d = ei[Ne + e]; a = ea[e]; }
    else        { s = e - Ne; d = s; a = sump[0] * inv_ne; }
    int pos = atomicAdd(&cursor[d], 1);
    src_sorted[pos] = s;
    ea_sorted[pos] = a;
}

// ---------------------------------------------------------------------------
// GATv2 attention + aggregation (fp16 xl/xr), one block per dst node.
// ---------------------------------------------------------------------------
__global__ __launch_bounds__(256) void gat_aggregate_kernel(
    const f16* __restrict__ xl, const f16* __restrict__ xr,
    const float* __restrict__ we, const float* __restrict__ att,
    const float* __restrict__ bias,
    const int* __restrict__ offsets, const int* __restrict__ src_sorted,
    const float* __restrict__ ea_sorted,
    float* __restrict__ logit_buf, f16* __restrict__ out, int ldo, int N)
{
    __shared__ float s_xr[512], s_we[512], s_att[512];
    __shared__ float s_wmax[32], s_mx[8], s_den[8], s_rden[8];
    __shared__ float s_alpha[256];
    __shared__ int s_src[32];
    const int i = blockIdx.x;
    const int tid = threadIdx.x;
    s_xr[tid]       = (float)xr[(size_t)i * 512 + tid];
    s_xr[tid + 256] = (float)xr[(size_t)i * 512 + tid + 256];
    s_we[tid] = we[tid]; s_we[tid + 256] = we[tid + 256];
    s_att[tid] = att[tid]; s_att[tid + 256] = att[tid + 256];
    if (tid < 8) s_den[tid] = 0.f;
    __syncthreads();

    const int beg = offsets[i], end = offsets[i + 1];
    const int w = tid >> 6, lane = tid & 63;

    // pass A: logits (head pairs per 128-col chunk), running max
    float wm[4] = {-1e30f, -1e30f, -1e30f, -1e30f};
    for (int e = beg + w; e < end; e += 4) {
        int s = src_sorted[e];
        float a = ea_sorted[e];
        float part[4];
#pragma unroll
        for (int cc = 0; cc < 4; ++cc) {
            int col = cc * 128 + lane * 2;
            f16x2 xv = *(const f16x2*)&xl[(size_t)s * 512 + col];
            float v0 = (float)xv.x + s_xr[col]     + a * s_we[col];
            float v1 = (float)xv.y + s_xr[col + 1] + a * s_we[col + 1];
            v0 = (v0 > 0.f) ? v0 : 0.2f * v0;
            v1 = (v1 > 0.f) ? v1 : 0.2f * v1;
            part[cc] = v0 * s_att[col] + v1 * s_att[col + 1];
        }
#pragma unroll
        for (int off = 16; off; off >>= 1)
#pragma unroll
            for (int cc = 0; cc < 4; ++cc) part[cc] += __shfl_xor(part[cc], off);
        if ((lane & 31) == 0) {
            int hb = lane >> 5;
#pragma unroll
            for (int cc = 0; cc < 4; ++cc) {
                logit_buf[(size_t)e * 8 + 2 * cc + hb] = part[cc];
                wm[cc] = fmaxf(wm[cc], part[cc]);
            }
        }
    }
    if ((lane & 31) == 0) {
        int hb = lane >> 5;
#pragma unroll
        for (int cc = 0; cc < 4; ++cc) s_wmax[w * 8 + 2 * cc + hb] = wm[cc];
    }
    __syncthreads();
    if (tid < 8) {
        float m = fmaxf(fmaxf(s_wmax[tid], s_wmax[8 + tid]),
                        fmaxf(s_wmax[16 + tid], s_wmax[24 + tid]));
        s_mx[tid] = m;
    }
    __syncthreads();

    // pass B: exp + denom
    for (int e = beg + tid; e < end; e += 256) {
#pragma unroll
        for (int h = 0; h < 8; ++h) {
            float ex = __expf(logit_buf[(size_t)e * 8 + h] - s_mx[h]);
            logit_buf[(size_t)e * 8 + h] = ex;
            atomicAdd(&s_den[h], ex);
        }
    }
    __syncthreads();
    if (tid < 8) s_rden[tid] = 1.f / s_den[tid];
    __syncthreads();

    // pass C: weighted aggregation, thread owns col pair (2*tid, 2*tid+1)
    float acc0 = 0.f, acc1 = 0.f;
    const int c2 = tid * 2, hh = tid >> 5;
    for (int chunk = beg; chunk < end; chunk += 32) {
        int cnt = min(32, end - chunk);
        if (tid < cnt) s_src[tid] = src_sorted[chunk + tid];
        int eo = tid >> 3, hq = tid & 7;
        if (eo < cnt) s_alpha[tid] = logit_buf[(size_t)(chunk + eo) * 8 + hq] * s_rden[hq];
        __syncthreads();
        for (int j = 0; j < cnt; ++j) {
            int s = s_src[j];
            f16x2 xv = *(const f16x2*)&xl[(size_t)s * 512 + c2];
            float al = s_alpha[j * 8 + hh];
            acc0 += al * (float)xv.x;
            acc1 += al * (float)xv.y;
        }
        __syncthreads();
    }
    float v0 = acc0 + bias[c2];
    float v1 = acc1 + bias[c2 + 1];
    v0 = (v0 > 0.f) ? v0 : __expf(v0) - 1.f;
    v1 = (v1 > 0.f) ? v1 : __expf(v1) - 1.f;
    f16x2 ov; ov.x = (f16)v0; ov.y = (f16)v1;
    *(f16x2*)&out[(size_t)i * ldo + c2] = ov;
}

// node (fp16, stride 512 @off applied by caller) -> fused cols 0..255
__global__ void nodecopy_kernel(const f16* __restrict__ node, f16* __restrict__ fused, int Nn) {
    int idx = blockIdx.x * 256 + threadIdx.x;
    if (idx >= Nn * 256) return;
    int m = idx >> 8, c = idx & 255;
    fused[(size_t)m * 768 + c] = node[(size_t)m * 512 + c];
}

// fc2: out[n] = H[n,:512] . w + b (fp32)
__global__ void fc2_kernel(const float* __restrict__ H, const float* __restrict__ w,
                           const float* __restrict__ b, float* __restrict__ out, int N) {
    int wv = threadIdx.x >> 6, lane = threadIdx.x & 63;
    int node = blockIdx.x * 4 + wv;
    if (node >= N) return;
    float s = 0.f;
#pragma unroll
    for (int j = 0; j < 8; ++j)
        s += H[(size_t)node * 512 + j * 64 + lane] * w[j * 64 + lane];
#pragma unroll
    for (int off = 32; off; off >>= 1) s += __shfl_xor(s, off, 64);
    if (lane == 0) out[node] = s + b[0];
}

// ---------------------------------------------------------------------------
extern "C" void kernel_launch(void* const* d_in, const int* in_sizes, int n_in,
                              void* d_out, int out_size, void* d_ws, size_t ws_size,
                              hipStream_t stream) {
    const float* x_seq     = (const float*)d_in[0];
    const int*   edge_index= (const int*)d_in[1];
    const float* edge_attr = (const float*)d_in[2];
    const float* w_ih0 = (const float*)d_in[3];
    const float* w_hh0 = (const float*)d_in[4];
    const float* b_ih0 = (const float*)d_in[5];
    const float* b_hh0 = (const float*)d_in[6];
    const float* w_ih1 = (const float*)d_in[7];
    const float* w_hh1 = (const float*)d_in[8];
    const float* b_ih1 = (const float*)d_in[9];
    const float* b_hh1 = (const float*)d_in[10];
    const float* g0_wl = (const float*)d_in[11];
    const float* g0_bl = (const float*)d_in[12];
    const float* g0_wr = (const float*)d_in[13];
    const float* g0_br = (const float*)d_in[14];
    const float* g0_we = (const float*)d_in[15];
    const float* g0_att= (const float*)d_in[16];
    const float* g0_bias=(const float*)d_in[17];
    const float* g1_wl = (const float*)d_in[18];
    const float* g1_bl = (const float*)d_in[19];
    const float* g1_wr = (const float*)d_in[20];
    const float* g1_br = (const float*)d_in[21];
    const float* g1_we = (const float*)d_in[22];
    const float* g1_att= (const float*)d_in[23];
    const float* g1_bias=(const float*)d_in[24];
    const float* fc1_w = (const float*)d_in[25];
    const float* fc1_b = (const float*)d_in[26];
    const float* fc2_w = (const float*)d_in[27];
    const float* fc2_b = (const float*)d_in[28];
    float* out = (float*)d_out;

    const int Nn = in_sizes[0] / (60 * 16);   // 10000
    const int Ne = in_sizes[1] / 2;           // 320000
    const int Etot = Ne + Nn;
    const int MT = (Nn + 127) / 128;          // 79
    const int Mpad = MT * 128;                // 10112

    size_t off = 0;
    auto alloc = [&](size_t bytes) -> void* {
        void* r = (char*)d_ws + off;
        off += (bytes + 255) & ~(size_t)255;
        return r;
    };
    f16* W0t   = (f16*)alloc((size_t)1024 * 288 * 2);
    f16* W1t   = (f16*)alloc((size_t)1024 * 512 * 2);
    float* b40 = (float*)alloc(1024 * 4);
    float* b41 = (float*)alloc(1024 * 4);
    f16* Wg0l  = (f16*)alloc((size_t)512 * 256 * 2);
    f16* Wg0r  = (f16*)alloc((size_t)512 * 256 * 2);
    f16* Wg1l  = (f16*)alloc((size_t)512 * 512 * 2);
    f16* Wg1r  = (f16*)alloc((size_t)512 * 512 * 2);
    f16* Wfc1  = (f16*)alloc((size_t)512 * 768 * 2);
    f16* A0b[2]; A0b[0] = (f16*)alloc((size_t)Mpad * 288 * 2);
                 A0b[1] = (f16*)alloc((size_t)Mpad * 288 * 2);
    f16* A1b[2]; A1b[0] = (f16*)alloc((size_t)Mpad * 512 * 2);
                 A1b[1] = (f16*)alloc((size_t)Mpad * 512 * 2);
    float* c0  = (float*)alloc((size_t)Mpad * 256 * 4);
    float* c1  = (float*)alloc((size_t)Mpad * 256 * 4);
    f16* xlbuf = (f16*)alloc((size_t)Mpad * 512 * 2);
    f16* xrbuf = (f16*)alloc((size_t)Mpad * 512 * 2);
    f16* gbuf  = (f16*)alloc((size_t)Mpad * 512 * 2);
    f16* fused = (f16*)alloc((size_t)Mpad * 768 * 2);
    float* hfc1= (float*)alloc((size_t)Mpad * 512 * 4);
    float* logit_buf = (float*)alloc((size_t)Etot * 8 * 4);
    int* counts  = (int*)alloc((size_t)Nn * 4);
    int* offsets = (int*)alloc((size_t)(Nn + 1) * 4);
    int* cursor  = (int*)alloc((size_t)Nn * 4);
    int* src_sorted = (int*)alloc((size_t)Etot * 4);
    float* ea_sorted = (float*)alloc((size_t)Etot * 4);
    float* meanp = (float*)alloc(256);

    // ---- weight / state prep (every call: ws is re-poisoned) ----
    prep_w0_kernel<<<dim3((1024 * 288 + 255) / 256), 256, 0, stream>>>(w_ih0, w_hh0, W0t);
    prep_w1_kernel<<<dim3((1024 * 512 + 255) / 256), 256, 0, stream>>>(w_ih1, w_hh1, W1t);
    prep_bias4_kernel<<<dim3(4), 256, 0, stream>>>(b_ih0, b_hh0, b40);
    prep_bias4_kernel<<<dim3(4), 256, 0, stream>>>(b_ih1, b_hh1, b41);
    prep_wt_kernel<<<dim3((256 * 512 + 255) / 256), 256, 0, stream>>>(g0_wl, Wg0l, 256, 512);
    prep_wt_kernel<<<dim3((256 * 512 + 255) / 256), 256, 0, stream>>>(g0_wr, Wg0r, 256, 512);
    prep_wt_kernel<<<dim3((512 * 512 + 255) / 256), 256, 0, stream>>>(g1_wl, Wg1l, 512, 512);
    prep_wt_kernel<<<dim3((512 * 512 + 255) / 256), 256, 0, stream>>>(g1_wr, Wg1r, 512, 512);
    prep_wt_kernel<<<dim3((768 * 512 + 255) / 256), 256, 0, stream>>>(fc1_w, Wfc1, 768, 512);
    hipMemsetAsync(A0b[0], 0, (size_t)Mpad * 288 * 2, stream);
    hipMemsetAsync(A1b[0], 0, (size_t)Mpad * 512 * 2, stream);
    hipMemsetAsync(c0, 0, (size_t)Mpad * 256 * 4, stream);
    hipMemsetAsync(c1, 0, (size_t)Mpad * 256 * 4, stream);
    prep_x0_kernel<<<dim3((Nn * 16 + 255) / 256), 256, 0, stream>>>(x_seq, A0b[0], Nn);

    // ---- edge prep (CSR by dst) ----
    hipMemsetAsync(meanp, 0, 4, stream);
    hipMemsetAsync(counts, 0, (size_t)Nn * 4, stream);
    mean_sum_kernel<<<dim3(256), 256, 0, stream>>>(edge_attr, Ne, meanp);
    hist_kernel<<<dim3((Etot + 255) / 256), 256, 0, stream>>>(edge_index, Ne, Nn, counts);
    scan_kernel<<<dim3(1), 256, 0, stream>>>(counts, offsets, Nn);
    hipMemcpyAsync(cursor, offsets, (size_t)Nn * 4, hipMemcpyDeviceToDevice, stream);
    scatter_kernel<<<dim3((Etot + 255) / 256), 256, 0, stream>>>(
        edge_index, edge_attr, meanp, 1.0f / (float)Ne, Ne, Nn, cursor, src_sorted, ea_sorted);

    // ---- 2-layer LSTM, 60 steps (f16 MFMA) ----
    dim3 lgrid(MT, 8);
    for (int t = 0; t < 60; ++t) {
        // layer 0: A = A0b[t&1] (K=288: x|h0|pad), h0 -> A1b[t&1] cols 0..255
        //          and -> A0b[(t+1)&1] cols 16..271 ; x_{t+1} -> A0b[(t+1)&1] cols 0..15
        lstm_mfma_kernel<<<lgrid, 256, 0, stream>>>(
            A0b[t & 1], 288, 288, W0t, b40, c0,
            A1b[t & 1], 512, 0,
            A0b[(t + 1) & 1], 288, 16,
            (t < 59) ? x_seq : nullptr, t + 1, Nn);
        // layer 1: A = A1b[t&1] (K=512: h0|h1), h1 -> A1b[(t+1)&1] cols 256..511
        lstm_mfma_kernel<<<lgrid, 256, 0, stream>>>(
            A1b[t & 1], 512, 512, W1t, b41, c1,
            A1b[(t + 1) & 1], 512, 256,
            nullptr, 0, 0,
            nullptr, 0, Nn);
    }
    const f16* node = A1b[0] + 256;   // h1 at t=59 landed in A1b[0] cols 256..511

    // ---- GAT layer 1 ----
    dim3 ggrid(MT, 4);
    gemm16_kernel<<<ggrid, 256, 0, stream>>>(node, 512, Wg0l, 256, g0_bl, xlbuf, nullptr, 512, 0, Nn);
    gemm16_kernel<<<ggrid, 256, 0, stream>>>(node, 512, Wg0r, 256, g0_br, xrbuf, nullptr, 512, 0, Nn);
    gat_aggregate_kernel<<<dim3(Nn), 256, 0, stream>>>(
        xlbuf, xrbuf, g0_we, g0_att, g0_bias, offsets, src_sorted, ea_sorted,
        logit_buf, gbuf, 512, Nn);

    // ---- GAT layer 2 (output straight into fused cols 256..767) ----
    gemm16_kernel<<<ggrid, 256, 0, stream>>>(gbuf, 512, Wg1l, 512, g1_bl, xlbuf, nullptr, 512, 0, Nn);
    gemm16_kernel<<<ggrid, 256, 0, stream>>>(gbuf, 512, Wg1r, 512, g1_br, xrbuf, nullptr, 512, 0, Nn);
    gat_aggregate_kernel<<<dim3(Nn), 256, 0, stream>>>(
        xlbuf, xrbuf, g1_we, g1_att, g1_bias, offsets, src_sorted, ea_sorted,
        logit_buf, fused + 256, 768, Nn);

    // ---- fusion MLP ----
    nodecopy_kernel<<<dim3((Nn * 256 + 255) / 256), 256, 0, stream>>>(node, fused, Nn);
    gemm16_kernel<<<ggrid, 256, 0, stream>>>(fused, 768, Wfc1, 768, fc1_b, nullptr, hfc1, 512, 1, Nn);
    fc2_kernel<<<dim3((Nn + 3) / 4), 256, 0, stream>>>(hfc1, fc2_w, fc2_b, out, Nn);
}